// Round 5
// baseline (757.510 us; speedup 1.0000x reference)
//
#include <hip/hip_runtime.h>

// TriPlaneField: 4-scale triplane bilinear sampling with cumulative-sum concat.
// Pipeline:
//   (1) transpose_all_kernel: [3,C,r,r] fp32 -> [3,r,r,C] fp16 for all 4
//       scales in one launch (fp16 halves bytes AND makes the whole grid set
//       ~150 MB = L3-resident).
//   (2) Morton sort of points (5 bits/dim): keys+hist -> prefix -> scatter.
//       Scatter emits sorted float4 records {x,y,z,orig_idx} so the gather
//       has no perm indirection and coalesced point loads.
//   (3) gather: p-major thread mapping (each block stays in ONE plane's
//       texture region) + bijective XCD-chunk swizzle (each XCD's L2 holds a
//       contiguous Morton range -> neighbor texel sharing hits L2 not L3).
//       half8 texel loads, fp32 lerp, non-temporal output stores.

#define TP_C 72
#define TP_PLANES 3
#define TP_SCALES 4
#define TP_INV_BOUNDS 0.625f  // 1/1.6
#define TP_CVEC8 (TP_C / 8)   // 9 half8 groups per (n,p)
#define TP_NXCD 8

typedef float    tp_f4 __attribute__((ext_vector_type(4)));
typedef _Float16 tp_h4 __attribute__((ext_vector_type(4)));
typedef _Float16 tp_h8 __attribute__((ext_vector_type(8)));

// Transpose tile counts per scale: 3*r*r/128 -> 96, 384, 1536, 6144 (cumulative)
#define TP_TILES0 96
#define TP_TILES1 480
#define TP_TILES2 2016
#define TP_TILES3 8160

#define TP_NBINS 32768  // 5 bits per dim, 3D Morton

// ------------- fused transpose: [3,C,r,r] fp32 -> [3,r,r,C] fp16 -------------
__global__ __launch_bounds__(256) void transpose_all_kernel(
    const float* __restrict__ g0, const float* __restrict__ g1,
    const float* __restrict__ g2, const float* __restrict__ g3,
    _Float16* __restrict__ t0, _Float16* __restrict__ t1,
    _Float16* __restrict__ t2, _Float16* __restrict__ t3)
{
    int b = blockIdx.x;
    const float* in;
    _Float16* out;
    int rr, tile;
    if (b < TP_TILES0)      { in = g0; out = t0; rr = 64 * 64;   tile = b; }
    else if (b < TP_TILES1) { in = g1; out = t1; rr = 128 * 128; tile = b - TP_TILES0; }
    else if (b < TP_TILES2) { in = g2; out = t2; rr = 256 * 256; tile = b - TP_TILES1; }
    else                    { in = g3; out = t3; rr = 512 * 512; tile = b - TP_TILES2; }

    int P0  = tile * 128;       // global pixel index within [0, 3*rr)
    int p   = P0 / rr;          // plane
    int px0 = P0 - p * rr;      // pixel within plane

    // LDS tile: [72 channels][128 pixels], row stride 129 floats (pad 1)
    __shared__ float lds[TP_C * 129];

    const float* inp = in + ((size_t)p * TP_C) * (size_t)rr + px0;
    int t = threadIdx.x;

    // Load: 72 rows x 32 float4, coalesced within each 512B channel row.
    #pragma unroll
    for (int j = 0; j < 9; ++j) {
        int idx = j * 256 + t;
        int c   = idx >> 5;           // channel row (0..71)
        int q4  = idx & 31;           // float4 index within row (0..31)
        tp_f4 v = __builtin_nontemporal_load(
            (const tp_f4*)(inp + (size_t)c * rr + q4 * 4));
        float* l = lds + c * 129 + q4 * 4;
        l[0] = v.x; l[1] = v.y; l[2] = v.z; l[3] = v.w;
    }
    __syncthreads();

    // Store fp16: tile output = 128 px * 72 ch * 2B = 18432B contiguous.
    _Float16* outp = out + (size_t)P0 * TP_C;
    #pragma unroll
    for (int j = 0; j < 9; ++j) {
        int idx = j * 256 + t;
        int q   = idx / 18;
        int c4  = idx - q * 18;
        const float* l = lds + (c4 * 4) * 129 + q;
        tp_h4 hv;
        hv.x = (_Float16)l[0 * 129];
        hv.y = (_Float16)l[1 * 129];
        hv.z = (_Float16)l[2 * 129];
        hv.w = (_Float16)l[3 * 129];
        *(tp_h4*)(outp + (size_t)idx * 4) = hv;
    }
}

// ---------------- Morton sort ----------------
__device__ __forceinline__ unsigned tp_expand5(unsigned v) {
    unsigned r = (v & 1);
    r |= (v & 2)  << 2;
    r |= (v & 4)  << 4;
    r |= (v & 8)  << 6;
    r |= (v & 16) << 8;
    return r;
}

__global__ __launch_bounds__(256) void keys_kernel(
    const float* __restrict__ pts, unsigned* __restrict__ keys,
    unsigned* __restrict__ hist, int N)
{
    int n = blockIdx.x * 256 + threadIdx.x;
    if (n >= N) return;
    float nx = fminf(fmaxf(-pts[n * 3 + 0] * TP_INV_BOUNDS, -1.f), 1.f);
    float ny = fminf(fmaxf(-pts[n * 3 + 1] * TP_INV_BOUNDS, -1.f), 1.f);
    float nz = fminf(fmaxf(-pts[n * 3 + 2] * TP_INV_BOUNDS, -1.f), 1.f);
    int qx = min(31, max(0, (int)((nx + 1.f) * 16.f)));
    int qy = min(31, max(0, (int)((ny + 1.f) * 16.f)));
    int qz = min(31, max(0, (int)((nz + 1.f) * 16.f)));
    unsigned key = tp_expand5((unsigned)qx)
                 | (tp_expand5((unsigned)qy) << 1)
                 | (tp_expand5((unsigned)qz) << 2);
    keys[n] = key;
    atomicAdd(&hist[key], 1u);
}

__global__ __launch_bounds__(1024) void prefix_kernel(
    const unsigned* __restrict__ hist, unsigned* __restrict__ binoff)
{
    __shared__ unsigned part[1024];
    int t = threadIdx.x;
    unsigned local[32];
    unsigned s = 0;
    #pragma unroll
    for (int i = 0; i < 32; ++i) { local[i] = hist[t * 32 + i]; s += local[i]; }
    part[t] = s;
    __syncthreads();
    for (int off = 1; off < 1024; off <<= 1) {
        unsigned v = (t >= off) ? part[t - off] : 0u;
        __syncthreads();
        part[t] += v;
        __syncthreads();
    }
    unsigned run = (t == 0) ? 0u : part[t - 1];
    #pragma unroll
    for (int i = 0; i < 32; ++i) { binoff[t * 32 + i] = run; run += local[i]; }
}

// Scatter: emit sorted float4 {x, y, z, bitcast(orig index)} — removes perm
// indirection + random pts reads from the gather's dependent-load chain.
__global__ __launch_bounds__(256) void scatter_kernel(
    const float* __restrict__ pts,
    const unsigned* __restrict__ keys, unsigned* __restrict__ binoff,
    float* __restrict__ spts, int N)
{
    int n = blockIdx.x * 256 + threadIdx.x;
    if (n >= N) return;
    unsigned pos = atomicAdd(&binoff[keys[n]], 1u);
    tp_f4 rec;
    rec.x = pts[n * 3 + 0];
    rec.y = pts[n * 3 + 1];
    rec.z = pts[n * 3 + 2];
    rec.w = __uint_as_float((unsigned)n);
    *(tp_f4*)(spts + (size_t)pos * 4) = rec;
}

// ------------- gather: bilinear sample from fp16 channel-last grids -------------
// p-major mapping: tid = p*(N*9) + ns*9 + cv. Bijective XCD-chunk swizzle on
// blockIdx (m204 formula) so each XCD's L2 serves one contiguous Morton range.
__global__ __launch_bounds__(256) void triplane_gather_kernel(
    const float* __restrict__ spts,
    const _Float16* __restrict__ t0,
    const _Float16* __restrict__ t1,
    const _Float16* __restrict__ t2,
    const _Float16* __restrict__ t3,
    float* __restrict__ out,
    int N, int nwg)
{
    // bijective XCD swizzle: orig -> chunked logical block id
    int orig = blockIdx.x;
    int xcd  = orig % TP_NXCD;
    int q    = nwg / TP_NXCD;
    int r    = nwg % TP_NXCD;
    int wgid = (xcd < r ? xcd * (q + 1) : r * (q + 1) + (xcd - r) * q) + orig / TP_NXCD;

    int idx = wgid * 256 + (int)threadIdx.x;
    int per_plane = N * TP_CVEC8;
    int total = TP_PLANES * per_plane;
    if (idx >= total) return;

    int p   = idx / per_plane;
    int rem = idx - p * per_plane;
    int ns  = rem / TP_CVEC8;         // sorted point index
    int cv  = rem - ns * TP_CVEC8;    // half8 channel group (0..8)

    tp_f4 sp = *(const tp_f4*)(spts + (size_t)ns * 4);
    int n = (int)__float_as_uint(sp.w);

    float nx = -sp.x * TP_INV_BOUNDS;
    float ny = -sp.y * TP_INV_BOUNDS;
    float nz = -sp.z * TP_INV_BOUNDS;

    float cx, cy;
    if (p == 0)      { cx = nx; cy = ny; }
    else if (p == 1) { cx = nx; cy = nz; }
    else             { cx = ny; cy = nz; }

    const _Float16* grids[TP_SCALES] = { t0, t1, t2, t3 };
    const int       res[TP_SCALES]   = { 64, 128, 256, 512 };

    float acc[8];
    #pragma unroll
    for (int k = 0; k < 8; ++k) acc[k] = 0.f;

    float* outrow = out + (size_t)n * (TP_SCALES * TP_PLANES * TP_C)
                        + (size_t)p * TP_C + cv * 8;

    #pragma unroll
    for (int s = 0; s < TP_SCALES; ++s) {
        const int r2 = res[s];
        const float rm1 = (float)(r2 - 1);

        float fx = (cx + 1.0f) * 0.5f * rm1;
        float fy = (cy + 1.0f) * 0.5f * rm1;
        fx = fminf(fmaxf(fx, 0.0f), rm1);
        fy = fminf(fmaxf(fy, 0.0f), rm1);

        float x0f = floorf(fx);
        float y0f = floorf(fy);
        float wx = fx - x0f;
        float wy = fy - y0f;
        int x0 = (int)x0f;
        int y0 = (int)y0f;
        int x1 = min(x0 + 1, r2 - 1);
        int y1 = min(y0 + 1, r2 - 1);

        const _Float16* g = grids[s] + ((size_t)p * r2 * r2) * TP_C + (size_t)cv * 8;
        tp_h8 v00 = *(const tp_h8*)(g + ((size_t)y0 * r2 + x0) * TP_C);
        tp_h8 v01 = *(const tp_h8*)(g + ((size_t)y0 * r2 + x1) * TP_C);
        tp_h8 v10 = *(const tp_h8*)(g + ((size_t)y1 * r2 + x0) * TP_C);
        tp_h8 v11 = *(const tp_h8*)(g + ((size_t)y1 * r2 + x1) * TP_C);

        float iwx = 1.0f - wx;
        float iwy = 1.0f - wy;

        #pragma unroll
        for (int k = 0; k < 8; ++k) {
            float a00 = (float)v00[k];
            float a01 = (float)v01[k];
            float a10 = (float)v10[k];
            float a11 = (float)v11[k];
            float top = a00 * iwx + a01 * wx;
            float bot = a10 * iwx + a11 * wx;
            acc[k] += top * iwy + bot * wy;
        }

        tp_f4 lo = { acc[0], acc[1], acc[2], acc[3] };
        tp_f4 hi = { acc[4], acc[5], acc[6], acc[7] };
        float* orow = outrow + s * (TP_PLANES * TP_C);
        __builtin_nontemporal_store(lo, (tp_f4*)orow);
        __builtin_nontemporal_store(hi, (tp_f4*)(orow + 4));
    }
}

extern "C" void kernel_launch(void* const* d_in, const int* in_sizes, int n_in,
                              void* d_out, int out_size, void* d_ws, size_t ws_size,
                              hipStream_t stream) {
    const float* pts = (const float*)d_in[0];
    const float* g[TP_SCALES] = {
        (const float*)d_in[1], (const float*)d_in[2],
        (const float*)d_in[3], (const float*)d_in[4] };
    float* out = (float*)d_out;

    const int res[TP_SCALES] = { 64, 128, 256, 512 };
    int N = in_sizes[0] / 3;

    // ws layout: [hist | binoff | keys | spts(float4) | fp16 grids], 16B aligned
    unsigned* hist   = (unsigned*)d_ws;
    unsigned* binoff = hist + TP_NBINS;
    unsigned* keys   = binoff + TP_NBINS;
    size_t spts_off = (size_t)2 * TP_NBINS + (size_t)N;
    spts_off = (spts_off + 3) & ~(size_t)3;       // 16B align (u32 units)
    float* spts = (float*)d_ws + spts_off;
    size_t meta = spts_off + (size_t)4 * N;
    meta = (meta + 3) & ~(size_t)3;

    _Float16* tg[TP_SCALES];
    _Float16* tgbase = (_Float16*)((float*)d_ws + meta);
    size_t off = 0;
    for (int s = 0; s < TP_SCALES; ++s) {
        tg[s] = tgbase + off;
        off += (size_t)TP_PLANES * TP_C * res[s] * res[s];
    }

    (void)hipMemsetAsync(hist, 0, TP_NBINS * sizeof(unsigned), stream);

    int pblocks = (N + 255) / 256;
    keys_kernel<<<pblocks, 256, 0, stream>>>(pts, keys, hist, N);

    transpose_all_kernel<<<TP_TILES3, 256, 0, stream>>>(
        g[0], g[1], g[2], g[3], tg[0], tg[1], tg[2], tg[3]);

    prefix_kernel<<<1, 1024, 0, stream>>>(hist, binoff);
    scatter_kernel<<<pblocks, 256, 0, stream>>>(pts, keys, binoff, spts, N);

    int total = TP_PLANES * N * TP_CVEC8;
    int block = 256;
    int nwg = (total + block - 1) / block;
    triplane_gather_kernel<<<nwg, block, 0, stream>>>(
        spts, tg[0], tg[1], tg[2], tg[3], out, N, nwg);
}

// Round 7
// 691.236 us; speedup vs baseline: 1.0959x; 1.0959x over previous
//
#include <hip/hip_runtime.h>

// TriPlaneField: 4-scale triplane bilinear sampling with cumulative-sum concat.
// Pipeline:
//   (1) transpose_all_kernel: [3,C,r,r] fp32 -> [3,r,r,C] fp16 for all 4
//       scales in one launch (fp16 halves bytes AND makes the whole grid set
//       ~150 MB = L3-resident).
//   (2) Morton sort of points (5 bits/dim): keys+hist -> prefix -> scatter.
//       Scatter emits sorted float4 records {x,y,z,orig_idx}: no perm
//       indirection, coalesced point loads in the gather.
//   (3) gather: POINT-major mapping (cv innermost, p middle) so the 27
//       threads of one point write its full 864B-per-scale output row
//       contiguously (r5 post-mortem: p-major split rows into 288B pieces ->
//       WRITE_SIZE +50% from partial-line RMW). Bijective XCD-chunk swizzle
//       keeps each XCD's L2 on one contiguous Morton range. half8 texel
//       loads, fp32 lerp, non-temporal output stores.

#define TP_C 72
#define TP_PLANES 3
#define TP_SCALES 4
#define TP_INV_BOUNDS 0.625f  // 1/1.6
#define TP_CVEC8 (TP_C / 8)   // 9 half8 groups per (n,p)
#define TP_NXCD 8

typedef float    tp_f4 __attribute__((ext_vector_type(4)));
typedef _Float16 tp_h4 __attribute__((ext_vector_type(4)));
typedef _Float16 tp_h8 __attribute__((ext_vector_type(8)));

// Transpose tile counts per scale: 3*r*r/128 -> 96, 384, 1536, 6144 (cumulative)
#define TP_TILES0 96
#define TP_TILES1 480
#define TP_TILES2 2016
#define TP_TILES3 8160

#define TP_NBINS 32768  // 5 bits per dim, 3D Morton

// ------------- fused transpose: [3,C,r,r] fp32 -> [3,r,r,C] fp16 -------------
__global__ __launch_bounds__(256) void transpose_all_kernel(
    const float* __restrict__ g0, const float* __restrict__ g1,
    const float* __restrict__ g2, const float* __restrict__ g3,
    _Float16* __restrict__ t0, _Float16* __restrict__ t1,
    _Float16* __restrict__ t2, _Float16* __restrict__ t3)
{
    int b = blockIdx.x;
    const float* in;
    _Float16* out;
    int rr, tile;
    if (b < TP_TILES0)      { in = g0; out = t0; rr = 64 * 64;   tile = b; }
    else if (b < TP_TILES1) { in = g1; out = t1; rr = 128 * 128; tile = b - TP_TILES0; }
    else if (b < TP_TILES2) { in = g2; out = t2; rr = 256 * 256; tile = b - TP_TILES1; }
    else                    { in = g3; out = t3; rr = 512 * 512; tile = b - TP_TILES2; }

    int P0  = tile * 128;       // global pixel index within [0, 3*rr)
    int p   = P0 / rr;          // plane
    int px0 = P0 - p * rr;      // pixel within plane

    // LDS tile: [72 channels][128 pixels], row stride 129 floats (pad 1)
    __shared__ float lds[TP_C * 129];

    const float* inp = in + ((size_t)p * TP_C) * (size_t)rr + px0;
    int t = threadIdx.x;

    // Load: 72 rows x 32 float4, coalesced within each 512B channel row.
    #pragma unroll
    for (int j = 0; j < 9; ++j) {
        int idx = j * 256 + t;
        int c   = idx >> 5;           // channel row (0..71)
        int q4  = idx & 31;           // float4 index within row (0..31)
        tp_f4 v = __builtin_nontemporal_load(
            (const tp_f4*)(inp + (size_t)c * rr + q4 * 4));
        float* l = lds + c * 129 + q4 * 4;
        l[0] = v.x; l[1] = v.y; l[2] = v.z; l[3] = v.w;
    }
    __syncthreads();

    // Store fp16: tile output = 128 px * 72 ch * 2B = 18432B contiguous.
    _Float16* outp = out + (size_t)P0 * TP_C;
    #pragma unroll
    for (int j = 0; j < 9; ++j) {
        int idx = j * 256 + t;
        int q   = idx / 18;
        int c4  = idx - q * 18;
        const float* l = lds + (c4 * 4) * 129 + q;
        tp_h4 hv;
        hv.x = (_Float16)l[0 * 129];
        hv.y = (_Float16)l[1 * 129];
        hv.z = (_Float16)l[2 * 129];
        hv.w = (_Float16)l[3 * 129];
        *(tp_h4*)(outp + (size_t)idx * 4) = hv;
    }
}

// ---------------- Morton sort ----------------
__device__ __forceinline__ unsigned tp_expand5(unsigned v) {
    unsigned r = (v & 1);
    r |= (v & 2)  << 2;
    r |= (v & 4)  << 4;
    r |= (v & 8)  << 6;
    r |= (v & 16) << 8;
    return r;
}

__global__ __launch_bounds__(256) void keys_kernel(
    const float* __restrict__ pts, unsigned* __restrict__ keys,
    unsigned* __restrict__ hist, int N)
{
    int n = blockIdx.x * 256 + threadIdx.x;
    if (n >= N) return;
    float nx = fminf(fmaxf(-pts[n * 3 + 0] * TP_INV_BOUNDS, -1.f), 1.f);
    float ny = fminf(fmaxf(-pts[n * 3 + 1] * TP_INV_BOUNDS, -1.f), 1.f);
    float nz = fminf(fmaxf(-pts[n * 3 + 2] * TP_INV_BOUNDS, -1.f), 1.f);
    int qx = min(31, max(0, (int)((nx + 1.f) * 16.f)));
    int qy = min(31, max(0, (int)((ny + 1.f) * 16.f)));
    int qz = min(31, max(0, (int)((nz + 1.f) * 16.f)));
    unsigned key = tp_expand5((unsigned)qx)
                 | (tp_expand5((unsigned)qy) << 1)
                 | (tp_expand5((unsigned)qz) << 2);
    keys[n] = key;
    atomicAdd(&hist[key], 1u);
}

__global__ __launch_bounds__(1024) void prefix_kernel(
    const unsigned* __restrict__ hist, unsigned* __restrict__ binoff)
{
    __shared__ unsigned part[1024];
    int t = threadIdx.x;
    unsigned local[32];
    unsigned s = 0;
    #pragma unroll
    for (int i = 0; i < 32; ++i) { local[i] = hist[t * 32 + i]; s += local[i]; }
    part[t] = s;
    __syncthreads();
    for (int off = 1; off < 1024; off <<= 1) {
        unsigned v = (t >= off) ? part[t - off] : 0u;
        __syncthreads();
        part[t] += v;
        __syncthreads();
    }
    unsigned run = (t == 0) ? 0u : part[t - 1];
    #pragma unroll
    for (int i = 0; i < 32; ++i) { binoff[t * 32 + i] = run; run += local[i]; }
}

// Scatter: emit sorted float4 {x, y, z, bitcast(orig index)}.
__global__ __launch_bounds__(256) void scatter_kernel(
    const float* __restrict__ pts,
    const unsigned* __restrict__ keys, unsigned* __restrict__ binoff,
    float* __restrict__ spts, int N)
{
    int n = blockIdx.x * 256 + threadIdx.x;
    if (n >= N) return;
    unsigned pos = atomicAdd(&binoff[keys[n]], 1u);
    tp_f4 rec;
    rec.x = pts[n * 3 + 0];
    rec.y = pts[n * 3 + 1];
    rec.z = pts[n * 3 + 2];
    rec.w = __uint_as_float((unsigned)n);
    *(tp_f4*)(spts + (size_t)pos * 4) = rec;
}

// ------------- gather: bilinear sample from fp16 channel-last grids -------------
// Point-major mapping: idx = ns*27 + p*9 + cv -> 27 consecutive threads cover
// one point's full (3 planes x 9 cv) output = 864B contiguous per scale.
__global__ __launch_bounds__(256) void triplane_gather_kernel(
    const float* __restrict__ spts,
    const _Float16* __restrict__ t0,
    const _Float16* __restrict__ t1,
    const _Float16* __restrict__ t2,
    const _Float16* __restrict__ t3,
    float* __restrict__ out,
    int N, int nwg)
{
    // bijective XCD swizzle: each XCD gets a contiguous chunk of blocks
    // (= contiguous Morton point range -> shared texels stay in its L2)
    int orig = blockIdx.x;
    int xcd  = orig % TP_NXCD;
    int q    = nwg / TP_NXCD;
    int r    = nwg % TP_NXCD;
    int wgid = (xcd < r ? xcd * (q + 1) : r * (q + 1) + (xcd - r) * q) + orig / TP_NXCD;

    int idx = wgid * 256 + (int)threadIdx.x;
    int total = N * TP_PLANES * TP_CVEC8;
    if (idx >= total) return;

    int cv = idx % TP_CVEC8;          // half8 channel group (0..8) — innermost
    int t  = idx / TP_CVEC8;
    int p  = t % TP_PLANES;
    int ns = t / TP_PLANES;           // sorted point index

    tp_f4 sp = *(const tp_f4*)(spts + (size_t)ns * 4);
    int n = (int)__float_as_uint(sp.w);

    float nx = -sp.x * TP_INV_BOUNDS;
    float ny = -sp.y * TP_INV_BOUNDS;
    float nz = -sp.z * TP_INV_BOUNDS;

    float cx, cy;
    if (p == 0)      { cx = nx; cy = ny; }
    else if (p == 1) { cx = nx; cy = nz; }
    else             { cx = ny; cy = nz; }

    const _Float16* grids[TP_SCALES] = { t0, t1, t2, t3 };
    const int       res[TP_SCALES]   = { 64, 128, 256, 512 };

    float acc[8];
    #pragma unroll
    for (int k = 0; k < 8; ++k) acc[k] = 0.f;

    float* outrow = out + (size_t)n * (TP_SCALES * TP_PLANES * TP_C)
                        + (size_t)p * TP_C + cv * 8;

    #pragma unroll
    for (int s = 0; s < TP_SCALES; ++s) {
        const int r2 = res[s];
        const float rm1 = (float)(r2 - 1);

        float fx = (cx + 1.0f) * 0.5f * rm1;
        float fy = (cy + 1.0f) * 0.5f * rm1;
        fx = fminf(fmaxf(fx, 0.0f), rm1);
        fy = fminf(fmaxf(fy, 0.0f), rm1);

        float x0f = floorf(fx);
        float y0f = floorf(fy);
        float wx = fx - x0f;
        float wy = fy - y0f;
        int x0 = (int)x0f;
        int y0 = (int)y0f;
        int x1 = min(x0 + 1, r2 - 1);
        int y1 = min(y0 + 1, r2 - 1);

        const _Float16* g = grids[s] + ((size_t)p * r2 * r2) * TP_C + (size_t)cv * 8;
        tp_h8 v00 = *(const tp_h8*)(g + ((size_t)y0 * r2 + x0) * TP_C);
        tp_h8 v01 = *(const tp_h8*)(g + ((size_t)y0 * r2 + x1) * TP_C);
        tp_h8 v10 = *(const tp_h8*)(g + ((size_t)y1 * r2 + x0) * TP_C);
        tp_h8 v11 = *(const tp_h8*)(g + ((size_t)y1 * r2 + x1) * TP_C);

        float iwx = 1.0f - wx;
        float iwy = 1.0f - wy;

        #pragma unroll
        for (int k = 0; k < 8; ++k) {
            float a00 = (float)v00[k];
            float a01 = (float)v01[k];
            float a10 = (float)v10[k];
            float a11 = (float)v11[k];
            float top = a00 * iwx + a01 * wx;
            float bot = a10 * iwx + a11 * wx;
            acc[k] += top * iwy + bot * wy;
        }

        tp_f4 lo = { acc[0], acc[1], acc[2], acc[3] };
        tp_f4 hi = { acc[4], acc[5], acc[6], acc[7] };
        float* orow = outrow + s * (TP_PLANES * TP_C);
        __builtin_nontemporal_store(lo, (tp_f4*)orow);
        __builtin_nontemporal_store(hi, (tp_f4*)(orow + 4));
    }
}

extern "C" void kernel_launch(void* const* d_in, const int* in_sizes, int n_in,
                              void* d_out, int out_size, void* d_ws, size_t ws_size,
                              hipStream_t stream) {
    const float* pts = (const float*)d_in[0];
    const float* g[TP_SCALES] = {
        (const float*)d_in[1], (const float*)d_in[2],
        (const float*)d_in[3], (const float*)d_in[4] };
    float* out = (float*)d_out;

    const int res[TP_SCALES] = { 64, 128, 256, 512 };
    int N = in_sizes[0] / 3;

    // ws layout: [hist | binoff | keys | spts(float4) | fp16 grids], 16B aligned
    unsigned* hist   = (unsigned*)d_ws;
    unsigned* binoff = hist + TP_NBINS;
    unsigned* keys   = binoff + TP_NBINS;
    size_t spts_off = (size_t)2 * TP_NBINS + (size_t)N;
    spts_off = (spts_off + 3) & ~(size_t)3;       // 16B align (u32 units)
    float* spts = (float*)d_ws + spts_off;
    size_t meta = spts_off + (size_t)4 * N;
    meta = (meta + 3) & ~(size_t)3;

    _Float16* tg[TP_SCALES];
    _Float16* tgbase = (_Float16*)((float*)d_ws + meta);
    size_t off = 0;
    for (int s = 0; s < TP_SCALES; ++s) {
        tg[s] = tgbase + off;
        off += (size_t)TP_PLANES * TP_C * res[s] * res[s];
    }

    (void)hipMemsetAsync(hist, 0, TP_NBINS * sizeof(unsigned), stream);

    int pblocks = (N + 255) / 256;
    keys_kernel<<<pblocks, 256, 0, stream>>>(pts, keys, hist, N);

    transpose_all_kernel<<<TP_TILES3, 256, 0, stream>>>(
        g[0], g[1], g[2], g[3], tg[0], tg[1], tg[2], tg[3]);

    prefix_kernel<<<1, 1024, 0, stream>>>(hist, binoff);
    scatter_kernel<<<pblocks, 256, 0, stream>>>(pts, keys, binoff, spts, N);

    int total = N * TP_PLANES * TP_CVEC8;
    int block = 256;
    int nwg = (total + block - 1) / block;
    triplane_gather_kernel<<<nwg, block, 0, stream>>>(
        spts, tg[0], tg[1], tg[2], tg[3], out, N, nwg);
}